// Round 7
// baseline (443.766 us; speedup 1.0000x reference)
//
#include <hip/hip_runtime.h>

#define NFEAT 128
#define H 20
#define DH 64
#define SCAN_T 1024
#define BE2 128   // edges per k_mlp block (4 waves x 16 x 2 edges/lane)
#define NB 192    // private-histogram blocks (atomic-free counting sort)
#define HW 12800  // max histogram words (supports N <= 51200 bins, 4 u8 counters/word)

typedef __attribute__((ext_vector_type(8))) short short8;
typedef __attribute__((ext_vector_type(4))) float f32x4;

__device__ __forceinline__ unsigned short f2bf(float f) {
    union { float f; unsigned u; } v; v.f = f;
    unsigned r = v.u + 0x7fff + ((v.u >> 16) & 1);   // RNE
    return (unsigned short)(r >> 16);
}
__device__ __forceinline__ unsigned pk2(unsigned short a, unsigned short b) {
    return (unsigned)a | ((unsigned)b << 16);
}
// bf16 element j (0..7) of a uint4 viewed as 8 packed bf16 -> f32. j compile-time (unrolled).
__device__ __forceinline__ float bfel(uint4 v, int j) {
    unsigned word = (j < 2) ? v.x : (j < 4) ? v.y : (j < 6) ? v.z : v.w;
    unsigned u = (j & 1) ? (word & 0xFFFF0000u) : (word << 16);
    return __int_as_float((int)u);
}

// DPP 16-lane sum (within each 16-lane row): VALU pipe only. All 16 lanes get the total.
template <int CTRL>
__device__ __forceinline__ float dpp_add(float x) {
    int y = __builtin_amdgcn_update_dpp(0, __float_as_int(x), CTRL, 0xF, 0xF, true);
    return x + __int_as_float(y);
}
__device__ __forceinline__ float sum16(float x) {
    x = dpp_add<0xB1>(x);    // quad_perm [1,0,3,2]
    x = dpp_add<0x4E>(x);    // quad_perm [2,3,0,1]
    x = dpp_add<0x124>(x);   // row_ror:4
    x = dpp_add<0x128>(x);   // row_ror:8
    return x;
}

// ---------------- prep: zero deg/csum/bcat2 + pack decoder B-fragments ----------------
__global__ __launch_bounds__(256) void k_prep(const float* __restrict__ Wd1,
                                              unsigned short* __restrict__ Bd1,
                                              int* __restrict__ deg, int* __restrict__ csum,
                                              float* __restrict__ bcat2, int N) {
    int t = blockIdx.x * blockDim.x + threadIdx.x;
    if (t < N) deg[t] = 0;   // needed by the CSR-atomic fallback path
    if (t < 256) csum[t] = 0;
    if (t < 128) bcat2[t] = 0.f;   // [0:20 mu | 64:84 var], zero-padded
    if (t < 256) {
        int f = t >> 6, l = t & 63;
        int n = f * 16 + (l & 15);
#pragma unroll
        for (int j = 0; j < 8; j++) {
            int k = (l >> 4) * 8 + j;
            float v = (k < H) ? Wd1[k * DH + n] : 0.f;
            Bd1[(size_t)f * 512 + l * 8 + j] = f2bf(v);
        }
    }
}

// ================= atomic-free counting sort (main path) =================
// Per-block histogram of cols into packed u8x4 LDS counters; the atomic's return value
// IS the edge's within-(block,bin) rank -> stored (u8) so k_place needs no LDS replay.
__global__ __launch_bounds__(512) void k_hist(const int* __restrict__ cols,
                                              unsigned* __restrict__ hist, int* __restrict__ csum,
                                              unsigned char* __restrict__ rank,
                                              int E, int N) {
    __shared__ unsigned h[HW];
    __shared__ int cs[256];
    int wstride = (N + 3) >> 2;
    int nchunks = (N + 255) >> 8;
    for (int i = threadIdx.x; i < wstride; i += 512) h[i] = 0;
    if (threadIdx.x < 256) cs[threadIdx.x] = 0;
    __syncthreads();
    int chunk = (E + NB - 1) / NB;
    int beg = blockIdx.x * chunk, end = min(beg + chunk, E);
    for (int i = beg + threadIdx.x; i < end; i += 512) {
        int c = __builtin_nontemporal_load(cols + i);
        int sh = (c & 3) * 8;
        unsigned old = atomicAdd(&h[c >> 2], 1u << sh);   // per-(block,bin) count < 256
        rank[i] = (unsigned char)((old >> sh) & 0xFF);
    }
    __syncthreads();
    unsigned* dst = hist + (size_t)blockIdx.x * wstride;
    for (int i = threadIdx.x; i < wstride; i += 512) {
        unsigned w = h[i];
        dst[i] = w;                                    // coalesced dump
        if (w) {
            int s = (w & 0xFF) + ((w >> 8) & 0xFF) + ((w >> 16) & 0xFF) + (w >> 24);
            atomicAdd(&cs[i >> 6], s);                 // word i covers bins 4i..4i+3 -> chunk i>>6
        }
    }
    __syncthreads();
    for (int j = threadIdx.x; j < nchunks; j += 512)
        if (cs[j]) atomicAdd(&csum[j], cs[j]);
}

// Exclusive scan of <=256 chunk sums (single block).
__global__ __launch_bounds__(256) void k_scansmall(const int* __restrict__ chunkSum,
                                                   int* __restrict__ chunkOff, int nb) {
    __shared__ int sc[256];
    int t = threadIdx.x;
    int v0 = (t < nb) ? chunkSum[t] : 0;
    sc[t] = v0;
    __syncthreads();
    for (int off = 1; off < 256; off <<= 1) {
        int v = (t >= off) ? sc[t - off] : 0;
        __syncthreads();
        sc[t] += v;
        __syncthreads();
    }
    if (t < nb) chunkOff[t] = sc[t] - v0;   // exclusive
}

// SINGLE-PASS bases: read hist once, cache per-block counts in packed registers
// (fully unrolled -> compile-time indices, no scratch), emit deg + offsets + delta.
__global__ __launch_bounds__(256) void k_bases(const unsigned* __restrict__ hist,
                                               const int* __restrict__ chunkOff,
                                               unsigned char* __restrict__ delta,
                                               int* __restrict__ offsets, int* __restrict__ deg,
                                               int N, int E) {
    __shared__ int sc[256];
    int c = blockIdx.x * 256 + threadIdx.x;
    int wstride = (N + 3) >> 2;
    int sh = (c & 3) * 8;
    bool valid = c < N;
    int cw = valid ? (c >> 2) : 0;
    unsigned cnt[NB / 4];   // NB u8 counts packed 4-per-word, compile-time indexed
    int d = 0;
#pragma unroll
    for (int b = 0; b < NB; b++) {
        unsigned w = hist[(size_t)b * wstride + cw];
        unsigned byte = (w >> sh) & 0xFF;
        if ((b & 3) == 0) cnt[b >> 2] = byte;
        else cnt[b >> 2] |= byte << ((b & 3) * 8);
        d += (int)byte;
    }
    if (!valid) d = 0;
    sc[threadIdx.x] = d;
    __syncthreads();
    for (int off = 1; off < 256; off <<= 1) {
        int v = (threadIdx.x >= off) ? sc[threadIdx.x - off] : 0;
        __syncthreads();
        sc[threadIdx.x] += v;
        __syncthreads();
    }
    if (valid) {
        int base = chunkOff[blockIdx.x] + sc[threadIdx.x] - d;   // global exclusive prefix
        offsets[c] = base;
        deg[c] = d;
        int run = 0;   // deg[c] < 256 -> fits u8
#pragma unroll
        for (int b = 0; b < NB; b++) {
            delta[(size_t)b * N + c] = (unsigned char)run;       // coalesced across threads
            run += (int)((cnt[b >> 2] >> ((b & 3) * 8)) & 0xFF);
        }
    }
    if (blockIdx.x == 0 && threadIdx.x == 0) offsets[N] = E;
}

// Pure scatter placement: no LDS, no atomics, full occupancy.
// pos = offsets[c] + delta[block(e)][c] + rank[e]  (bijective onto [0,E)).
__global__ __launch_bounds__(256) void k_place(const int* __restrict__ rows, const int* __restrict__ cols,
                                               const int* __restrict__ offsets,
                                               const unsigned char* __restrict__ delta,
                                               const unsigned char* __restrict__ rank,
                                               unsigned short* __restrict__ srcs, int E, int N, int chunk) {
    int e = blockIdx.x * 256 + threadIdx.x;
    if (e >= E) return;
    int c = cols[e];
    int r = rows[e];
    int b = e / chunk;   // matches k_hist's block partition
    int pos = offsets[c] + (int)delta[(size_t)b * N + c] + (int)rank[e];
    srcs[pos] = (unsigned short)r;
}

// ---------------- CSR fallback path (global atomics; used only if ws too small) ----------------
__global__ __launch_bounds__(256) void k_deg(const int* __restrict__ cols, int* __restrict__ deg, int E) {
    int t = blockIdx.x * blockDim.x + threadIdx.x;
    if (t < E) atomicAdd(&deg[cols[t]], 1);
}

__global__ __launch_bounds__(SCAN_T) void k_scan(const int* __restrict__ deg, int* __restrict__ offsets,
                                                 int* __restrict__ cursor, int N) {
    __shared__ int sums[SCAN_T];
    int t = threadIdx.x;
    int chunk = (N + SCAN_T - 1) / SCAN_T;
    int beg = t * chunk;
    int end = min(beg + chunk, N);
    int s = 0;
    for (int i = beg; i < end; i++) s += deg[i];
    sums[t] = s;
    __syncthreads();
    for (int off = 1; off < SCAN_T; off <<= 1) {
        int v = (t >= off) ? sums[t - off] : 0;
        __syncthreads();
        sums[t] += v;
        __syncthreads();
    }
    int run = (t == 0) ? 0 : sums[t - 1];
    for (int i = beg; i < end; i++) {
        offsets[i] = run;
        cursor[i] = run;
        run += deg[i];
    }
    if (t == SCAN_T - 1) offsets[N] = sums[SCAN_T - 1];
}

__global__ __launch_bounds__(256) void k_bucket_csr(const int* __restrict__ rows, const int* __restrict__ cols,
                                                    int* __restrict__ cursor, int* __restrict__ srcs, int E) {
    int e = blockIdx.x * blockDim.x + threadIdx.x;
    if (e >= E) return;
    int pos = atomicAdd(&cursor[cols[e]], 1);
    srcs[pos] = rows[e];
}

// ---------------- xs = (x @ W_gc) * rsqrt(deg+1) ----------------
__global__ __launch_bounds__(256) void k_xw_xs(const float* __restrict__ x, const float* __restrict__ Wgc,
                                               const int* __restrict__ deg,
                                               float* __restrict__ xs, int N) {
    __shared__ float Ws[NFEAT * H];
    for (int i = threadIdx.x; i < NFEAT * H; i += blockDim.x) Ws[i] = Wgc[i];
    __syncthreads();
    int n = blockIdx.x * blockDim.x + threadIdx.x;
    if (n >= N) return;
    float acc[H];
#pragma unroll
    for (int j = 0; j < H; j++) acc[j] = 0.f;
    const float4* x4 = (const float4*)(x + (size_t)n * NFEAT);
#pragma unroll 4
    for (int k4 = 0; k4 < NFEAT / 4; k4++) {
        float4 xv = x4[k4];
#pragma unroll
        for (int s = 0; s < 4; s++) {
            float xk = (s == 0) ? xv.x : (s == 1) ? xv.y : (s == 2) ? xv.z : xv.w;
            const float4* wrow = (const float4*)(Ws + (k4 * 4 + s) * H);
#pragma unroll
            for (int q = 0; q < 5; q++) {
                float4 w = wrow[q];
                acc[q * 4 + 0] += xk * w.x;
                acc[q * 4 + 1] += xk * w.y;
                acc[q * 4 + 2] += xk * w.z;
                acc[q * 4 + 3] += xk * w.w;
            }
        }
    }
    float di = rsqrtf((float)(deg[n] + 1));
    float4* o = (float4*)(xs + (size_t)n * H);
#pragma unroll
    for (int q = 0; q < 5; q++)
        o[q] = make_float4(acc[q * 4 + 0] * di, acc[q * 4 + 1] * di, acc[q * 4 + 2] * di, acc[q * 4 + 3] * di);
}

// ---------------- gather: 16 lanes per node, DPP reduce, emit PACKED head-projection tables ----------------
// PA[n] = x1n @ {Wmu,Wvar}[0:20] (r-side), PB[n] = rows 20:40 (c-side). Row = 80 B (40 u16):
//   u16 [0:8)=mu0-7 [8:16)=var0-7 [16:24)=mu8-15 [24:32)=var8-15 [32:36)=mu16-19 [36:40)=var16-19
// (no padding -> tables 2 x 4 MB). nid head contribution folded into bcat2 (mu j->[j], var j->[64+j]).
template <typename IT>
__device__ __forceinline__ void gather_core16(const float* __restrict__ xs, const IT* __restrict__ idx,
                                              int beg, int end, int n, int sl, int degn,
                                              const float* __restrict__ bgc,
                                              unsigned short* __restrict__ PAo, unsigned short* __restrict__ PBo,
                                              int nid, const float* __restrict__ Wmu, const float* __restrict__ Wvar,
                                              const float* __restrict__ bmu, const float* __restrict__ bvar,
                                              float* __restrict__ bcat2) {
    float acc[H];
    if (sl == 0) {   // self-loop term counted once
        const float4* self = (const float4*)(xs + (size_t)n * H);
#pragma unroll
        for (int q = 0; q < 5; q++) {
            float4 v = self[q];
            acc[q * 4 + 0] = v.x; acc[q * 4 + 1] = v.y; acc[q * 4 + 2] = v.z; acc[q * 4 + 3] = v.w;
        }
    } else {
#pragma unroll
        for (int j = 0; j < H; j++) acc[j] = 0.f;
    }
#pragma unroll 2
    for (int i = beg + sl; i < end; i += 16) {
        int r = (int)__builtin_nontemporal_load(idx + i);   // touch-once: keep xs L2-resident
        const float4* p = (const float4*)(xs + (size_t)r * H);
#pragma unroll
        for (int q = 0; q < 5; q++) {
            float4 v = p[q];
            acc[q * 4 + 0] += v.x; acc[q * 4 + 1] += v.y; acc[q * 4 + 2] += v.z; acc[q * 4 + 3] += v.w;
        }
    }
#pragma unroll
    for (int j = 0; j < H; j++) acc[j] = sum16(acc[j]);    // all 16 lanes hold the totals
    float di = rsqrtf((float)(degn + 1));
    float x1f[H];
#pragma unroll
    for (int j = 0; j < H; j++) x1f[j] = fmaxf(di * acc[j] + bgc[j], 0.f);

    // ---- head projections: 80 values/node (4 parts x 20 dims), 5 per lane ----
#pragma unroll
    for (int t = 0; t < 5; t++) {
        int v = sl + 16 * t;          // 0..79
        int part = v / 20;            // 0:PAmu 1:PAvar 2:PBmu 3:PBvar
        int j = v - part * 20;        // 0..19
        const float* W = (part & 1) ? Wvar : Wmu;
        int k0 = (part < 2) ? 0 : 20;
        float s = 0.f;
#pragma unroll
        for (int k = 0; k < H; k++) s += x1f[k] * W[(k0 + k) * H + j];
        unsigned short* T = (part < 2) ? PAo : PBo;
        int off = (j < 16) ? ((j >> 3) * 16 + (part & 1) * 8 + (j & 7))
                           : (32 + (part & 1) * 4 + (j - 16));
        T[(size_t)n * 40 + off] = f2bf(s);
    }

    if (n == nid) {   // nid head-bias fold: 16 lanes split the 40 bias dots
#pragma unroll
        for (int base = 0; base < 48; base += 16) {
            int jj = base + sl;
            if (jj < 40) {
                bool ismu = jj < 20;
                int col = ismu ? jj : jj - 20;
                const float* W = ismu ? Wmu : Wvar;
                float s = ismu ? bmu[col] : bvar[col];
#pragma unroll
                for (int k = 0; k < H; k++) s += x1f[k] * W[(2 * H + k) * H + col];
                bcat2[ismu ? col : 64 + col] = s;
            }
        }
    }
}

__global__ __launch_bounds__(256) void k_gather_csr16(const float* __restrict__ xs, const unsigned short* __restrict__ srcs,
                                                      const int* __restrict__ offsets, const int* __restrict__ deg,
                                                      const float* __restrict__ bgc,
                                                      unsigned short* __restrict__ PAo, unsigned short* __restrict__ PBo,
                                                      const int* __restrict__ node_id,
                                                      const float* __restrict__ Wmu, const float* __restrict__ Wvar,
                                                      const float* __restrict__ bmu, const float* __restrict__ bvar,
                                                      float* __restrict__ bcat2, int N) {
    int wave = (blockIdx.x * 256 + threadIdx.x) >> 6;
    int lane = threadIdx.x & 63;
    int n = wave * 4 + (lane >> 4);
    if (n >= N) return;
    gather_core16(xs, srcs, offsets[n], offsets[n + 1], n, lane & 15, deg[n], bgc, PAo, PBo,
                  node_id[0], Wmu, Wvar, bmu, bvar, bcat2);
}

__global__ __launch_bounds__(256) void k_gather_csr(const float* __restrict__ xs, const int* __restrict__ srcs,
                                                    const int* __restrict__ offsets, const int* __restrict__ deg,
                                                    const float* __restrict__ bgc,
                                                    unsigned short* __restrict__ PAo, unsigned short* __restrict__ PBo,
                                                    const int* __restrict__ node_id,
                                                    const float* __restrict__ Wmu, const float* __restrict__ Wvar,
                                                    const float* __restrict__ bmu, const float* __restrict__ bvar,
                                                    float* __restrict__ bcat2, int N) {
    int wave = (blockIdx.x * 256 + threadIdx.x) >> 6;
    int lane = threadIdx.x & 63;
    int n = wave * 4 + (lane >> 4);
    if (n >= N) return;
    gather_core16(xs, srcs, offsets[n], offsets[n + 1], n, lane & 15, deg[n], bgc, PAo, PBo,
                  node_id[0], Wmu, Wvar, bmu, bvar, bcat2);
}

// ---------------- per-lane z-fragment builder (R5 structure, 80 B rows) ----------------
// Lane (q,m) of a wave builds the decoder A-fragment (k-dims q*8..q*8+7) for one edge:
// z[k] = PAmu[r][k] + PBmu[c][k] + bm[k] + exp(PAvar+PBvar+bv) * noise[k].
__device__ __forceinline__ short8 build_a2(const unsigned short* __restrict__ PA,
                                           const unsigned short* __restrict__ PBt,
                                           const float* __restrict__ noise_n,
                                           int em, int r, int c, int q,
                                           const float (&bm)[8], const float (&bv)[8]) {
    uint4 pam = {0, 0, 0, 0}, pav = pam, pbm = pam, pbv = pam;
    float nz[8];
#pragma unroll
    for (int j = 0; j < 8; j++) nz[j] = 0.f;
    if (q < 2) {
        const char* pa = (const char*)PA + (size_t)r * 80 + q * 32;
        const char* pb = (const char*)PBt + (size_t)c * 80 + q * 32;
        pam = *(const uint4*)pa;  pav = *(const uint4*)(pa + 16);
        pbm = *(const uint4*)pb;  pbv = *(const uint4*)(pb + 16);
        const float* np = noise_n + (size_t)em * H + q * 8;
        float4 n0 = *(const float4*)np;
        float4 n1 = *(const float4*)(np + 4);
        nz[0] = n0.x; nz[1] = n0.y; nz[2] = n0.z; nz[3] = n0.w;
        nz[4] = n1.x; nz[5] = n1.y; nz[6] = n1.z; nz[7] = n1.w;
    } else if (q == 2) {
        const char* pa = (const char*)PA + (size_t)r * 80 + 64;
        const char* pb = (const char*)PBt + (size_t)c * 80 + 64;
        uint2 am = *(const uint2*)pa;        // mu16-19
        uint2 av = *(const uint2*)(pa + 8);  // var16-19
        uint2 bm2 = *(const uint2*)pb;
        uint2 bv2 = *(const uint2*)(pb + 8);
        pam.x = am.x; pam.y = am.y;
        pav.x = av.x; pav.y = av.y;
        pbm.x = bm2.x; pbm.y = bm2.y;
        pbv.x = bv2.x; pbv.y = bv2.y;
        float4 n0 = *(const float4*)(noise_n + (size_t)em * H + 16);
        nz[0] = n0.x; nz[1] = n0.y; nz[2] = n0.z; nz[3] = n0.w;
    }
    unsigned zp[4];
#pragma unroll
    for (int jj = 0; jj < 4; jj++) {
        unsigned short zh[2];
#pragma unroll
        for (int h2 = 0; h2 < 2; h2++) {
            int j = jj * 2 + h2;
            float zmu = bfel(pam, j) + bfel(pbm, j) + bm[j];
            float zva = bfel(pav, j) + bfel(pbv, j) + bv[j];
            float z = zmu + __expf(zva) * nz[j];
            z = (q * 8 + j < 20) ? z : 0.f;   // zero k-padding
            zh[h2] = f2bf(z);
        }
        zp[jj] = pk2(zh[0], zh[1]);
    }
    union { unsigned u[4]; short8 s; } au;
    au.u[0] = zp[0]; au.u[1] = zp[1]; au.u[2] = zp[2]; au.u[3] = zp[3];
    return au.s;
}

// ---------------- fused per-edge MLP: LDS-free, barrier-free, 2 edges/lane ----------------
__global__ __launch_bounds__(256) void k_mlp(
    const unsigned short* __restrict__ PA, const unsigned short* __restrict__ PBt,
    const int* __restrict__ rows, const int* __restrict__ cols,
    const float* __restrict__ noise_n, const float* __restrict__ noise_u,
    const unsigned short* __restrict__ Bd1g,
    const float* __restrict__ bcat2, const float* __restrict__ b_d1,
    const float* __restrict__ W_d2, const float* __restrict__ b_d2,
    float* __restrict__ out, int E) {

    int tid = threadIdx.x;
    int e0 = blockIdx.x * BE2;
    int l = tid & 63, w = tid >> 6;
    int m = l & 15, q = l >> 4;

    // ---- shared per-q biases (same for both edges); bcat2 zero-padded so q=2 over-reads are 0 ----
    float bm[8], bv[8];
#pragma unroll
    for (int j = 0; j < 8; j++) { bm[j] = 0.f; bv[j] = 0.f; }
    if (q < 3) {
        float4 b0 = *(const float4*)(bcat2 + q * 8);
        float4 b1 = *(const float4*)(bcat2 + q * 8 + 4);
        bm[0] = b0.x; bm[1] = b0.y; bm[2] = b0.z; bm[3] = b0.w;
        bm[4] = b1.x; bm[5] = b1.y; bm[6] = b1.z; bm[7] = b1.w;
        float4 v0 = *(const float4*)(bcat2 + 64 + q * 8);
        float4 v1 = *(const float4*)(bcat2 + 64 + q * 8 + 4);
        bv[0] = v0.x; bv[1] = v0.y; bv[2] = v0.z; bv[3] = v0.w;
        bv[4] = v1.x; bv[5] = v1.y; bv[6] = v1.z; bv[7] = v1.w;
    }

    // ---- edge pair: ea0 = e0 + w*16 + m, ea1 = ea0 + 64 ----
    int ea0 = e0 + w * 16 + m;
    int ea1 = ea0 + 64;
    int em0 = (ea0 < E) ? ea0 : E - 1;
    int em1 = (ea1 < E) ? ea1 : E - 1;
    int r0 = rows[em0], c0 = cols[em0];
    int r1 = rows[em1], c1 = cols[em1];

    short8 a2_0 = (q < 3) ? build_a2(PA, PBt, noise_n, em0, r0, c0, q, bm, bv)
                          : short8{0, 0, 0, 0, 0, 0, 0, 0};
    short8 a2_1 = (q < 3) ? build_a2(PA, PBt, noise_n, em1, r1, c1, q, bm, bv)
                          : short8{0, 0, 0, 0, 0, 0, 0, 0};

    // ---- decoder: shared Bd1 fragment, 2 MFMAs per t4 (one per edge) ----
    float p0a = 0.f, p1a = 0.f, p2a = 0.f, p3a = 0.f;
    float p0b = 0.f, p1b = 0.f, p2b = 0.f, p3b = 0.f;
#pragma unroll
    for (int t4 = 0; t4 < 4; t4++) {
        short8 bb = *(const short8*)(Bd1g + t4 * 512 + l * 8);
        f32x4 za = {0.f, 0.f, 0.f, 0.f};
        f32x4 zb = {0.f, 0.f, 0.f, 0.f};
        za = __builtin_amdgcn_mfma_f32_16x16x32_bf16(a2_0, bb, za, 0, 0, 0);
        zb = __builtin_amdgcn_mfma_f32_16x16x32_bf16(a2_1, bb, zb, 0, 0, 0);
        int col = t4 * 16 + m;
        float bias = b_d1[col], wo = W_d2[col];
        p0a += fmaxf(za[0] + bias, 0.f) * wo;
        p1a += fmaxf(za[1] + bias, 0.f) * wo;
        p2a += fmaxf(za[2] + bias, 0.f) * wo;
        p3a += fmaxf(za[3] + bias, 0.f) * wo;
        p0b += fmaxf(zb[0] + bias, 0.f) * wo;
        p1b += fmaxf(zb[1] + bias, 0.f) * wo;
        p2b += fmaxf(zb[2] + bias, 0.f) * wo;
        p3b += fmaxf(zb[3] + bias, 0.f) * wo;
    }
    p0a = sum16(p0a); p1a = sum16(p1a); p2a = sum16(p2a); p3a = sum16(p3a);
    p0b = sum16(p0b); p1b = sum16(p1b); p2b = sum16(p2b); p3b = sum16(p3b);
    if (m < 4) {
        float swa = (m == 0) ? p0a : (m == 1) ? p1a : (m == 2) ? p2a : p3a;
        float swb = (m == 0) ? p0b : (m == 1) ? p1b : (m == 2) ? p2b : p3b;
        int eA = e0 + w * 16 + q * 4 + m;
        int eB = eA + 64;
        if (eA < E) {
            float sw = fmaxf(swa + b_d2[0], 0.f);
            float u = noise_u[eA];
            float ev = 0.9999f - 0.9998f * u;
            out[eA] = ev / (ev + (1.f - ev) * __expf(-sw));
        }
        if (eB < E) {
            float sw = fmaxf(swb + b_d2[0], 0.f);
            float u = noise_u[eB];
            float ev = 0.9999f - 0.9998f * u;
            out[eB] = ev / (ev + (1.f - ev) * __expf(-sw));
        }
    }
}

extern "C" void kernel_launch(void* const* d_in, const int* in_sizes, int n_in,
                              void* d_out, int out_size, void* d_ws, size_t ws_size,
                              hipStream_t stream) {
    const int N = in_sizes[0] / NFEAT;   // 50000
    const int E = in_sizes[1] / 2;       // 1600000

    const float* x       = (const float*)d_in[0];
    const int*   ei      = (const int*)d_in[1];
    const int*   rows    = ei;
    const int*   cols    = ei + E;
    const int*   node_id = (const int*)d_in[2];
    const float* noise_n = (const float*)d_in[3];
    const float* noise_u = (const float*)d_in[4];
    const float* Wgc  = (const float*)d_in[5];
    const float* bgc  = (const float*)d_in[6];
    const float* Wmu  = (const float*)d_in[7];
    const float* bmu  = (const float*)d_in[8];
    const float* Wvar = (const float*)d_in[9];
    const float* bvar = (const float*)d_in[10];
    const float* Wd1  = (const float*)d_in[11];
    const float* bd1  = (const float*)d_in[12];
    const float* Wd2  = (const float*)d_in[13];
    const float* bd2  = (const float*)d_in[14];
    float* out = (float*)d_out;

    const int B = 256;
    int gN  = (N + B - 1) / B;
    int gG  = (N + 15) / 16;            // gather: 16 nodes per block (4 waves x 4 nodes)
    int gE  = (E + B - 1) / B;
    int gM  = (E + BE2 - 1) / BE2;
    int nBins = (N + 255) / 256;        // <= 256 for N <= 65536
    int chunk = (E + NB - 1) / NB;

    char* ws = (char*)d_ws;
    size_t wstride   = (size_t)((N + 3) >> 2);
    size_t pa_sz     = (((size_t)N * 80) + 255) & ~255ULL;
    size_t hist_sz   = ((NB * wstride * 4) + 255) & ~255ULL;
    size_t histreg   = (hist_sz > 2 * pa_sz) ? hist_sz : 2 * pa_sz;   // PA/PB alias dead hist
    // main-path layout (256B-aligned regions)
    size_t o_deg     = 0;
    size_t o_off     = o_deg  + (((size_t)N * 4 + 255) & ~255ULL);
    size_t o_csum    = o_off  + (((size_t)(N + 1) * 4 + 255) & ~255ULL);
    size_t o_coff    = o_csum + 1024;
    size_t o_hist    = o_coff + 1024;
    size_t o_delta   = o_hist  + histreg;
    size_t o_rank    = o_delta + (((size_t)NB * N + 255) & ~255ULL);
    size_t o_srcs    = o_rank  + (((size_t)E + 255) & ~255ULL);
    size_t o_xs      = o_srcs  + (((size_t)E * 2 + 255) & ~255ULL);
    size_t o_Bd1     = o_xs    + (((size_t)N * H * 4 + 255) & ~255ULL);
    size_t o_bcat2   = o_Bd1   + 4096;
    size_t need      = o_bcat2 + 512;

    bool main_path = (ws_size >= need) && (N <= 4 * HW) && (N < 65536) && (nBins <= 256);

    if (main_path) {
        int*   deg     = (int*)(ws + o_deg);
        int*   offsets = (int*)(ws + o_off);
        int*   csum    = (int*)(ws + o_csum);
        int*   coff    = (int*)(ws + o_coff);
        unsigned* hist = (unsigned*)(ws + o_hist);
        unsigned short* PA = (unsigned short*)(ws + o_hist);            // alias (hist dead after k_bases)
        unsigned short* PB = (unsigned short*)(ws + o_hist + pa_sz);
        unsigned char* delta = (unsigned char*)(ws + o_delta);
        unsigned char* rank  = (unsigned char*)(ws + o_rank);
        unsigned short* srcs = (unsigned short*)(ws + o_srcs);
        float* xs      = (float*)(ws + o_xs);
        unsigned short* Bd1  = (unsigned short*)(ws + o_Bd1);
        float* bcat2   = (float*)(ws + o_bcat2);

        k_prep<<<gN, B, 0, stream>>>(Wd1, Bd1, deg, csum, bcat2, N);
        k_hist<<<NB, 512, 0, stream>>>(cols, hist, csum, rank, E, N);
        k_scansmall<<<1, B, 0, stream>>>(csum, coff, nBins);
        k_bases<<<nBins, B, 0, stream>>>(hist, coff, delta, offsets, deg, N, E);
        k_xw_xs<<<gN, B, 0, stream>>>(x, Wgc, deg, xs, N);
        k_place<<<gE, B, 0, stream>>>(rows, cols, offsets, delta, rank, srcs, E, N, chunk);
        k_gather_csr16<<<gG, B, 0, stream>>>(xs, srcs, offsets, deg, bgc, PA, PB,
                                             node_id, Wmu, Wvar, bmu, bvar, bcat2, N);
        k_mlp<<<gM, B, 0, stream>>>(PA, PB, rows, cols, noise_n, noise_u,
                                    Bd1, bcat2, bd1, Wd2, bd2, out, E);
    } else {
        size_t f_deg   = 0;
        size_t f_off   = f_deg + (((size_t)N * 4 + 255) & ~255ULL);
        size_t f_cur   = f_off + (((size_t)(N + 1) * 4 + 255) & ~255ULL);
        size_t f_srcs  = f_cur + (((size_t)N * 4 + 255) & ~255ULL);
        size_t f_xs    = f_srcs + (((size_t)E * 4 + 255) & ~255ULL);
        size_t f_PA    = f_xs + (((size_t)N * H * 4 + 255) & ~255ULL);
        size_t f_PB    = f_PA + pa_sz;
        size_t f_Bd1   = f_PB + pa_sz;
        size_t f_bcat2 = f_Bd1 + 4096;

        int*   deg     = (int*)(ws + f_deg);
        int*   offsets = (int*)(ws + f_off);
        int*   cursor  = (int*)(ws + f_cur);
        int*   srcs    = (int*)(ws + f_srcs);
        float* xs      = (float*)(ws + f_xs);
        unsigned short* PA = (unsigned short*)(ws + f_PA);
        unsigned short* PB = (unsigned short*)(ws + f_PB);
        unsigned short* Bd1 = (unsigned short*)(ws + f_Bd1);
        float* bcat2   = (float*)(ws + f_bcat2);

        k_prep<<<gN, B, 0, stream>>>(Wd1, Bd1, deg, cursor, bcat2, N);
        k_deg<<<gE, B, 0, stream>>>(cols, deg, E);
        k_scan<<<1, SCAN_T, 0, stream>>>(deg, offsets, cursor, N);
        k_bucket_csr<<<gE, B, 0, stream>>>(rows, cols, cursor, srcs, E);
        k_xw_xs<<<gN, B, 0, stream>>>(x, Wgc, deg, xs, N);
        k_gather_csr<<<gG, B, 0, stream>>>(xs, srcs, offsets, deg, bgc, PA, PB,
                                           node_id, Wmu, Wvar, bmu, bvar, bcat2, N);
        k_mlp<<<gM, B, 0, stream>>>(PA, PB, rows, cols, noise_n, noise_u,
                                    Bd1, bcat2, bd1, Wd2, bd2, out, E);
    }
}